// Round 15
// baseline (641.975 us; speedup 1.0000x reference)
//
#include <hip/hip_runtime.h>
#include <stdint.h>

typedef unsigned short u16;
typedef unsigned int   u32;
typedef __attribute__((ext_vector_type(8))) short v8s;
typedef __attribute__((ext_vector_type(4))) float v4f;

#define NN  100000
#define NE  600000
#define NEL 200000

__device__ __forceinline__ float b2f(u16 u){ return __uint_as_float(((u32)u)<<16); }
__device__ __forceinline__ u16 f2b(float f){
  u32 u = __float_as_uint(f);
  u32 r = (u + 0x7FFFu + ((u>>16)&1u)) >> 16;   // RNE
  return (u16)r;
}
__device__ __forceinline__ void unpack8(uint4 v, float* o){
  o[0]=__uint_as_float(v.x<<16); o[1]=__uint_as_float(v.x&0xffff0000u);
  o[2]=__uint_as_float(v.y<<16); o[3]=__uint_as_float(v.y&0xffff0000u);
  o[4]=__uint_as_float(v.z<<16); o[5]=__uint_as_float(v.z&0xffff0000u);
  o[6]=__uint_as_float(v.w<<16); o[7]=__uint_as_float(v.w&0xffff0000u);
}
// mode: 1 = bf16, 0 = f32
__device__ __forceinline__ float ldf(const void* p, size_t i, int m){
  return m ? b2f(((const u16*)p)[i]) : ((const float*)p)[i];
}
__device__ __forceinline__ void ld16(const void* p, size_t off, int m, float* o){
  if (m){
    const uint4* q = (const uint4*)((const u16*)p + off);
    uint4 a=q[0], b=q[1]; unpack8(a,o); unpack8(b,o+8);
  } else {
    const float4* q = (const float4*)((const float*)p + off);
    float4 a=q[0],b=q[1],c=q[2],d=q[3];
    o[0]=a.x;o[1]=a.y;o[2]=a.z;o[3]=a.w; o[4]=b.x;o[5]=b.y;o[6]=b.z;o[7]=b.w;
    o[8]=c.x;o[9]=c.y;o[10]=c.z;o[11]=c.w; o[12]=d.x;o[13]=d.y;o[14]=d.z;o[15]=d.w;
  }
}
__device__ __forceinline__ void stf(void* p, size_t i, int m, float v){
  if (m) ((u16*)p)[i] = f2b(v); else ((float*)p)[i] = v;
}
// HW fp32 atomic (coarse-grained d_ws -> safe)
__device__ __forceinline__ void atomAdd(float* p, float v){ unsafeAtomicAdd(p, v); }

// ---------------- per-array dtype detector ----------------
__global__ void k_detect(const void* a0,const void* a3,const void* a6,const void* a7,
                         const void* a8,const void* a9,const void* a10,const void* a11,
                         const void* a12,const void* a13,const void* a14,const void* a15,
                         const void* a16,const void* a17,const void* a18,const void* a19,
                         const void* a20,const void* a21,const void* a23,
                         int* __restrict__ flags){
  const void* ptrs[19] = {a0,a3,a6,a7,a8,a9,a10,a11,a12,a13,a14,a15,a16,a17,a18,a19,a20,a21,a23};
  const int  idxs[19] = {0,3,6,7,8,9,10,11,12,13,14,15,16,17,18,19,20,21,23};
  int b = blockIdx.x;
  const u16* q = (const u16*)ptrs[b];
  u16 u = q[threadIdx.x];
  int e = (u>>7)&0xFF;
  bool good = (u==0) || (e>=110 && e<=141);
  unsigned long long m = __ballot(good);
  if (threadIdx.x==0) flags[idxs[b]] = (__popcll(m) >= 52) ? 1 : 0;
}

// ---------------- utility: zero / stub ----------------
__global__ __launch_bounds__(256) void k_zero(float* __restrict__ buf, int n){
  int i = blockIdx.x*256 + threadIdx.x;
  if (i < n) buf[i] = 0.f;
}
__global__ __launch_bounds__(256) void k_stub(u16* __restrict__ out, int n){
  int i = blockIdx.x*256 + threadIdx.x;
  if (i < n) out[i] = 0;
}

// ---------------- pack Wx2 once: bf16 k-pairs ----------------
__global__ __launch_bounds__(256) void k_pack(const void* __restrict__ Wx2,
                                              const int* __restrict__ flags,
                                              u32* __restrict__ Wxp){
  int m14 = flags[14];
  int i = blockIdx.x*256 + threadIdx.x;   // 8192 total
  int k2=i>>8, col=i&255;
  u16 lo = f2b(ldf(Wx2,(size_t)(2*k2)*256+col,m14));
  u16 hi = f2b(ldf(Wx2,(size_t)(2*k2+1)*256+col,m14));
  Wxp[i] = ((u32)hi<<16)|lo;
}

// ---------------- CSR build: hist -> scan -> scatter ----------------
__global__ __launch_bounds__(256) void k_hist(const int* __restrict__ ei, int* __restrict__ cnt){
  int e = blockIdx.x*256 + threadIdx.x;
  if (e < NE) atomicAdd(&cnt[ei[NE+e]], 1);
}
__global__ __launch_bounds__(256) void k_scan1(const int* __restrict__ cnt,
                                               int* __restrict__ row_ptr, int* __restrict__ bsum){
  __shared__ int sb[256];
  int i = blockIdx.x*256 + threadIdx.x, t = threadIdx.x;
  int c = (i < NN) ? cnt[i] : 0;
  sb[t] = c; __syncthreads();
  for (int off=1; off<256; off<<=1){
    int v = (t>=off) ? sb[t-off] : 0; __syncthreads();
    sb[t] += v; __syncthreads();
  }
  if (i < NN) row_ptr[i] = sb[t] - c;     // block-local exclusive
  if (t == 255) bsum[blockIdx.x] = sb[255];
}
__global__ __launch_bounds__(512) void k_scan2(const int* __restrict__ bsum, int* __restrict__ boff){
  __shared__ int sb[512];
  int t = threadIdx.x;
  int nblk = (NN+255)/256;   // 391
  int c = (t < nblk) ? bsum[t] : 0;
  sb[t] = c; __syncthreads();
  for (int off=1; off<512; off<<=1){
    int v = (t>=off) ? sb[t-off] : 0; __syncthreads();
    sb[t] += v; __syncthreads();
  }
  boff[t] = sb[t] - c;
}
__global__ __launch_bounds__(256) void k_scan3(int* __restrict__ row_ptr, const int* __restrict__ boff){
  int i = blockIdx.x*256 + threadIdx.x;
  if (i < NN) row_ptr[i] += boff[blockIdx.x];
  if (i == 0) row_ptr[NN] = NE;
}
// scatter + sorted payloads: perm[pos]=e, se[pos]=src|(etype<<20)
__global__ __launch_bounds__(256) void k_scatter(const int* __restrict__ ei, const int* __restrict__ etype,
                                                 const int* __restrict__ row_ptr,
                                                 int* __restrict__ cur, int* __restrict__ perm,
                                                 int* __restrict__ se){
  int e = blockIdx.x*256 + threadIdx.x;
  if (e < NE){
    int d = ei[NE+e];
    int pos = row_ptr[d] + atomicAdd(&cur[d], 1);
    perm[pos] = e;
    se[pos] = ei[e] | (etype[e]<<20);   // src < 2^20, type < 2^5
  }
}

// ---------------- fold edge-score projections ----------------
__global__ void k_fold(const void* __restrict__ We1, const void* __restrict__ ae1, const void* __restrict__ et1,
                       const void* __restrict__ We2, const void* __restrict__ ae2, const void* __restrict__ et2,
                       const int* __restrict__ flags,
                       float* We1a, float* et1a, float* We2a, float* et2a){
  int m7=flags[7], m12=flags[12], m9=flags[9], m15=flags[15], m20=flags[20], m17=flags[17];
  int t = threadIdx.x;
  if (t < 64){
    int k=t>>2, h=t&3; float s=0.f;
    for (int d=0; d<16; d++) s += ldf(We1,k*64+h*16+d,m7)*ldf(ae1,h*16+d,m12);
    We1a[t]=s;
  } else if (t < 152){
    int i=t-64; int k=i>>2, h=i&3; float s=0.f;
    for (int d=0; d<16; d++) s += ldf(et1,k*64+h*16+d,m9)*ldf(ae1,h*16+d,m12);
    et1a[i]=s;
  } else if (t < 216){
    int i=t-152; int k=i>>2, h=i&3; float s=0.f;
    for (int d=0; d<64; d++) s += ldf(We2,k*256+h*64+d,m15)*ldf(ae2,h*64+d,m20);
    We2a[i]=s;
  } else if (t < 304){
    int i=t-216; int k=i>>2, h=i&3; float s=0.f;
    for (int d=0; d<64; d++) s += ldf(et2,k*256+h*64+d,m17)*ldf(ae2,h*64+d,m20);
    et2a[i]=s;
  }
}

// ---------------- layer1 node projection ----------------
__global__ __launch_bounds__(256) void k1_node(
    const void* __restrict__ x, const int* __restrict__ ntype,
    const void* __restrict__ Wx1, const void* __restrict__ nt1, const void* __restrict__ res1,
    const void* __restrict__ as1, const void* __restrict__ ad1,
    const int* __restrict__ flags,
    float* __restrict__ h1, float* __restrict__ out1,
    float* __restrict__ ssrc1, float* __restrict__ sdst1){
  __shared__ float sWx[1024], sRes[1024], sA[64], sD[64], sNt[128];
  int m0=flags[0], m6=flags[6], m8=flags[8], m13=flags[13], m10=flags[10], m11=flags[11];
  for (int i=threadIdx.x;i<1024;i+=256){ sWx[i]=ldf(Wx1,i,m6); sRes[i]=ldf(res1,i,m13); }
  if (threadIdx.x<64){ sA[threadIdx.x]=ldf(as1,threadIdx.x,m10); sD[threadIdx.x]=ldf(ad1,threadIdx.x,m11); }
  if (threadIdx.x<128) sNt[threadIdx.x]=ldf(nt1,threadIdx.x,m8);
  __syncthreads();
  int n = blockIdx.x*256 + threadIdx.x;
  if (n >= NN) return;
  float xv[16]; ld16(x, (size_t)n*16, m0, xv);
  int nt = ntype[n];
  float xin[16];
  #pragma unroll
  for (int k=0;k<16;k++) xin[k] = xv[k] + sNt[nt*16+k];
  float ss[4]={0,0,0,0}, sd[4]={0,0,0,0};
  #pragma unroll
  for (int jq=0;jq<16;jq++){
    float sarr[4], rarr[4];
    #pragma unroll
    for (int m=0;m<4;m++){
      int j = jq*4+m;
      float s=0.f, r=0.f;
      #pragma unroll
      for (int k=0;k<16;k++){ s += xin[k]*sWx[k*64+j]; r += xv[k]*sRes[k*64+j]; }
      sarr[m]=s; rarr[m]=r;
      ss[j>>4] += s*sA[j];
      sd[j>>4] += s*sD[j];
    }
    ((float4*)(h1  + (size_t)n*64))[jq] = make_float4(sarr[0],sarr[1],sarr[2],sarr[3]);
    ((float4*)(out1+ (size_t)n*64))[jq] = make_float4(rarr[0],rarr[1],rarr[2],rarr[3]);
  }
  ((float4*)ssrc1)[n] = make_float4(ss[0],ss[1],ss[2],ss[3]);
  ((float4*)sdst1)[n] = make_float4(sd[0],sd[1],sd[2],sd[3]);
}

// ---------------- layer1 message: FUSED score + aggregate + factored projection ----------------
// R15: k_sed fused in. d == n in node-centric form, so sdst is one load/node;
// the score dot distributes over the lane layout: lane j holds ea[jk] (already
// loaded for gacc), partial = ea[jk]*We1a[jk*4+h], 4-level shfl_xor reduce
// within the 16-lane head group -> p (uniform per group; msg1 needs own-head
// only). psort/rank and both k_sed dispatches eliminated.
__global__ __launch_bounds__(256) void k_msg1(
    const void* __restrict__ eattr, const void* __restrict__ et1, const void* __restrict__ We1,
    const float* __restrict__ We1a, const float* __restrict__ et1a,
    const float* __restrict__ ssrc, const float* __restrict__ sdst,
    const float* __restrict__ h1,
    const int* __restrict__ row_ptr, const int* __restrict__ perm, const int* __restrict__ se,
    const int* __restrict__ flags,
    float* __restrict__ out1){
  __shared__ float sEt[22*64];
  __shared__ float sW1[16*64];    // 4KB We1
  __shared__ float sWa[64], sEa[88];
  __shared__ float sG[4][64];     // per-wave transpose slabs
  int m3=flags[3], m9=flags[9], m7=flags[7];
  for (int i=threadIdx.x;i<22*64;i+=256) sEt[i]=ldf(et1,i,m9);
  for (int i=threadIdx.x;i<16*64;i+=256) sW1[i]=ldf(We1,i,m7);
  if (threadIdx.x<64) sWa[threadIdx.x]=We1a[threadIdx.x];
  if (threadIdx.x<88) sEa[threadIdx.x]=et1a[threadIdx.x];
  __syncthreads();
  int j = threadIdx.x & 63;
  int h = j>>4, jk = j&15;
  int wid = threadIdx.x>>6;
  float wA = sWa[jk*4+h];         // per-lane score weight
  for (int it=0; it<8; ++it){
    int n = (blockIdx.x*4 + wid)*8 + it;
    float sdn = sdst[(size_t)n*4+h];
    int beg=row_ptr[n], end=row_ptr[n+1];
    float sp=0.f, acc=0.f, gacc=0.f;
    int i=beg;
    for (; i+1<end; i+=2){
      int st0=se[i], st1=se[i+1];
      int pe0=perm[i], pe1=perm[i+1];
      int s0=st0&0xFFFFF, t0=st0>>20;
      int s1=st1&0xFFFFF, t1=st1>>20;
      float ea0 = ldf(eattr,(size_t)pe0*16+jk,m3);
      float ea1 = ldf(eattr,(size_t)pe1*16+jk,m3);
      float hv0 = h1[(size_t)s0*64+j];
      float hv1 = h1[(size_t)s1*64+j];
      float ss0 = ssrc[(size_t)s0*4+h];
      float ss1 = ssrc[(size_t)s1*4+h];
      float sc0 = ea0*wA, sc1 = ea1*wA;
      sc0 += __shfl_xor(sc0,1); sc1 += __shfl_xor(sc1,1);
      sc0 += __shfl_xor(sc0,2); sc1 += __shfl_xor(sc1,2);
      sc0 += __shfl_xor(sc0,4); sc1 += __shfl_xor(sc1,4);
      sc0 += __shfl_xor(sc0,8); sc1 += __shfl_xor(sc1,8);
      float v0 = sEa[t0*4+h] + ss0 + sdn + sc0;
      float v1 = sEa[t1*4+h] + ss1 + sdn + sc1;
      v0 = v0>0.f ? v0 : 0.2f*v0;  v0 = fminf(v0,60.f);  float p0 = __expf(v0);
      v1 = v1>0.f ? v1 : 0.2f*v1;  v1 = fminf(v1,60.f);  float p1 = __expf(v1);
      sp   += p0 + p1;
      acc  += p0*(hv0+sEt[t0*64+j]) + p1*(hv1+sEt[t1*64+j]);
      gacc += p0*ea0 + p1*ea1;
    }
    if (i<end){
      int st0=se[i]; int pe0=perm[i];
      int s0=st0&0xFFFFF, t0=st0>>20;
      float ea0 = ldf(eattr,(size_t)pe0*16+jk,m3);
      float hv0 = h1[(size_t)s0*64+j];
      float ss0 = ssrc[(size_t)s0*4+h];
      float sc0 = ea0*wA;
      sc0 += __shfl_xor(sc0,1); sc0 += __shfl_xor(sc0,2);
      sc0 += __shfl_xor(sc0,4); sc0 += __shfl_xor(sc0,8);
      float v0 = sEa[t0*4+h] + ss0 + sdn + sc0;
      v0 = v0>0.f ? v0 : 0.2f*v0;  v0 = fminf(v0,60.f);  float p0 = __expf(v0);
      sp   += p0;
      acc  += p0*(hv0+sEt[t0*64+j]);
      gacc += p0*ea0;
    }
    float rd = 1.f/(sp+1e-16f);
    // in-wave transpose: g[h*16+k] == lane index j (jh*16+jk)
    sG[wid][j] = gacc*rd;          // same-wave produce/consume (lgkmcnt-ordered)
    float proj=0.f;
    #pragma unroll
    for (int k=0;k<16;k++) proj += sG[wid][h*16+k]*sW1[k*64+j];
    out1[(size_t)n*64+j] += acc*rd + proj;   // plain RMW: single owner
  }
}

// ---------------- layer1 finish + layer2 node projection ----------------
__global__ __launch_bounds__(256) void k5_node2(
    const int* __restrict__ ntype,
    const u32* __restrict__ Wxp, const void* __restrict__ nt2,
    const void* __restrict__ as2, const void* __restrict__ ad2,
    const int* __restrict__ flags,
    const float* __restrict__ out1, float* __restrict__ zfin,
    u16* __restrict__ h2, float* __restrict__ ssrc2, float* __restrict__ sdst2){
  __shared__ u32   sWp[32*256];     // 32KB
  __shared__ float sNt[512];
  __shared__ float sAs[256], sAd[256];
  __shared__ float sZ[4][8][64];    // 8KB
  __shared__ float sR[4][2][256];   // 8KB per-wave reduce slabs
  int m16=flags[16], m18=flags[18], m19=flags[19];
  for (int i=threadIdx.x;i<32*256;i+=256) sWp[i] = Wxp[i];
  for (int i=threadIdx.x;i<512;i+=256) sNt[i]=ldf(nt2,i,m16);
  sAs[threadIdx.x]=ldf(as2,threadIdx.x,m18);
  sAd[threadIdx.x]=ldf(ad2,threadIdx.x,m19);
  __syncthreads();
  int slot=threadIdx.x>>6, j=threadIdx.x&63;
  int base=(blockIdx.x*4+slot)*8;
  #pragma unroll
  for (int i=0;i<8;i++){
    int n=base+i;
    float z = out1[(size_t)n*64+j]; z = fmaxf(z, 0.f);   // relu
    zfin[(size_t)n*64+j] = z;                            // identity residual accumulator
    sZ[slot][i][j] = z + sNt[(ntype[n]<<6)|j];
  }
  __syncthreads();
  float acc[8][4];
  #pragma unroll
  for (int i=0;i<8;i++){ acc[i][0]=0;acc[i][1]=0;acc[i][2]=0;acc[i][3]=0; }
  for (int k2=0;k2<32;k2++){
    u32 w0p=sWp[k2*256+j], w1p=sWp[k2*256+64+j], w2p=sWp[k2*256+128+j], w3p=sWp[k2*256+192+j];
    float w0l=__uint_as_float(w0p<<16), w0h=__uint_as_float(w0p&0xffff0000u);
    float w1l=__uint_as_float(w1p<<16), w1h=__uint_as_float(w1p&0xffff0000u);
    float w2l=__uint_as_float(w2p<<16), w2h=__uint_as_float(w2p&0xffff0000u);
    float w3l=__uint_as_float(w3p<<16), w3h=__uint_as_float(w3p&0xffff0000u);
    #pragma unroll
    for (int i=0;i<8;i++){
      float2 zz = *(const float2*)&sZ[slot][i][k2*2];
      acc[i][0] += zz.x*w0l + zz.y*w0h;
      acc[i][1] += zz.x*w1l + zz.y*w1h;
      acc[i][2] += zz.x*w2l + zz.y*w2h;
      acc[i][3] += zz.x*w3l + zz.y*w3h;
    }
  }
  int g=j>>4, l=j&15;
  #pragma unroll
  for (int i=0;i<8;i++){
    int n=base+i;
    // transposed h2 layout [n][j*4+h]: one 8B store, matching msg2's uint2 gather
    u32 lo = (u32)f2b(acc[i][0]) | ((u32)f2b(acc[i][1])<<16);
    u32 hi = (u32)f2b(acc[i][2]) | ((u32)f2b(acc[i][3])<<16);
    *(uint2*)&h2[(size_t)n*256 + j*4] = make_uint2(lo,hi);
    // LDS-transpose reduce: head c partials at sR[slot][v][c*64+j]
    sR[slot][0][      j] = acc[i][0]*sAs[      j];
    sR[slot][0][ 64 + j] = acc[i][1]*sAs[ 64 + j];
    sR[slot][0][128 + j] = acc[i][2]*sAs[128 + j];
    sR[slot][0][192 + j] = acc[i][3]*sAs[192 + j];
    sR[slot][1][      j] = acc[i][0]*sAd[      j];
    sR[slot][1][ 64 + j] = acc[i][1]*sAd[ 64 + j];
    sR[slot][1][128 + j] = acc[i][2]*sAd[128 + j];
    sR[slot][1][192 + j] = acc[i][3]*sAd[192 + j];
    // same-wave produce/consume; same-array ordering enforced by lgkmcnt
    float4 v4 = *(const float4*)&sR[slot][0][g*64 + l*4];
    float4 w4 = *(const float4*)&sR[slot][1][g*64 + l*4];
    float vs = v4.x+v4.y+v4.z+v4.w;
    float vd = w4.x+w4.y+w4.z+w4.w;
    #pragma unroll
    for (int off=1; off<16; off<<=1){ vs += __shfl_xor(vs,off); vd += __shfl_xor(vd,off); }
    if (l==0){ ssrc2[(size_t)n*4+g]=vs; sdst2[(size_t)n*4+g]=vd; }
  }
}

// ---------------- layer2 message: FUSED score + aggregate ----------------
// R15: k_sed fused. Own-head p via 16-lane reduce; all-4-head p via 4 broadcast
// shfls (p uniform within each head group; lane h*16 holds head h's value).
__global__ __launch_bounds__(256) void k_msg2(
    const void* __restrict__ eattr, const void* __restrict__ et2,
    const float* __restrict__ We2a, const float* __restrict__ et2a,
    const float* __restrict__ ssrc, const float* __restrict__ sdst,
    const u16* __restrict__ h2,
    const int* __restrict__ row_ptr, const int* __restrict__ perm, const int* __restrict__ se,
    const int* __restrict__ flags,
    float* __restrict__ zfin, float* __restrict__ gsum){
  __shared__ float4 sEt4[22*64];   // 22.5KB: [t][j] = et2[t][h*64+j] for h=0..3
  __shared__ float sWa[64], sEa[88];
  int m3=flags[3], m17=flags[17];
  for (int i=threadIdx.x;i<22*64;i+=256){
    int t=i>>6, j=i&63;
    sEt4[i] = make_float4(ldf(et2,(size_t)t*256+j,m17),      ldf(et2,(size_t)t*256+64+j,m17),
                          ldf(et2,(size_t)t*256+128+j,m17),  ldf(et2,(size_t)t*256+192+j,m17));
  }
  if (threadIdx.x<64) sWa[threadIdx.x]=We2a[threadIdx.x];
  if (threadIdx.x<88) sEa[threadIdx.x]=et2a[threadIdx.x];
  __syncthreads();
  int j = threadIdx.x & 63;
  int jh = j>>4, jk = j&15;
  int wid = threadIdx.x>>6;
  float wA = sWa[jk*4+jh];
  for (int it=0; it<8; ++it){
    int n = (blockIdx.x*4 + wid)*8 + it;
    float sdn = sdst[(size_t)n*4+jh];
    int beg=row_ptr[n], end=row_ptr[n+1];
    float ds0=0,ds1=0,ds2=0,ds3=0;
    float pa0=0,pa1=0,pa2=0,pa3=0, gacc=0;
    int i=beg;
    for (; i+1<end; i+=2){
      int st0=se[i], st1=se[i+1];
      int pe0=perm[i], pe1=perm[i+1];
      int s0=st0&0xFFFFF, t0=st0>>20;
      int s1=st1&0xFFFFF, t1=st1>>20;
      float ea0 = ldf(eattr,(size_t)pe0*16+jk,m3);
      float ea1 = ldf(eattr,(size_t)pe1*16+jk,m3);
      uint2 hA = *(const uint2*)&h2[(size_t)s0*256 + j*4];
      uint2 hB = *(const uint2*)&h2[(size_t)s1*256 + j*4];
      float ss0 = ssrc[(size_t)s0*4+jh];
      float ss1 = ssrc[(size_t)s1*4+jh];
      float sc0 = ea0*wA, sc1 = ea1*wA;
      sc0 += __shfl_xor(sc0,1); sc1 += __shfl_xor(sc1,1);
      sc0 += __shfl_xor(sc0,2); sc1 += __shfl_xor(sc1,2);
      sc0 += __shfl_xor(sc0,4); sc1 += __shfl_xor(sc1,4);
      sc0 += __shfl_xor(sc0,8); sc1 += __shfl_xor(sc1,8);
      float v0 = sEa[t0*4+jh] + ss0 + sdn + sc0;
      float v1 = sEa[t1*4+jh] + ss1 + sdn + sc1;
      v0 = v0>0.f ? v0 : 0.2f*v0;  v0 = fminf(v0,60.f);  float p0 = __expf(v0);
      v1 = v1>0.f ? v1 : 0.2f*v1;  v1 = fminf(v1,60.f);  float p1 = __expf(v1);
      // broadcast all-4 head p's (uniform per 16-lane group)
      float q0x=__shfl(p0,0), q0y=__shfl(p0,16), q0z=__shfl(p0,32), q0w=__shfl(p0,48);
      float q1x=__shfl(p1,0), q1y=__shfl(p1,16), q1z=__shfl(p1,32), q1w=__shfl(p1,48);
      float4 eA = sEt4[t0*64+j], eB = sEt4[t1*64+j];
      ds0 += q0x+q1x; ds1 += q0y+q1y; ds2 += q0z+q1z; ds3 += q0w+q1w;
      pa0 += q0x*(__uint_as_float(hA.x<<16)        +eA.x) + q1x*(__uint_as_float(hB.x<<16)        +eB.x);
      pa1 += q0y*(__uint_as_float(hA.x&0xffff0000u)+eA.y) + q1y*(__uint_as_float(hB.x&0xffff0000u)+eB.y);
      pa2 += q0z*(__uint_as_float(hA.y<<16)        +eA.z) + q1z*(__uint_as_float(hB.y<<16)        +eB.z);
      pa3 += q0w*(__uint_as_float(hA.y&0xffff0000u)+eA.w) + q1w*(__uint_as_float(hB.y&0xffff0000u)+eB.w);
      gacc += p0*ea0 + p1*ea1;    // own-head p
    }
    if (i<end){
      int st0=se[i]; int pe0=perm[i];
      int s0=st0&0xFFFFF, t0=st0>>20;
      float ea0 = ldf(eattr,(size_t)pe0*16+jk,m3);
      uint2 hA = *(const uint2*)&h2[(size_t)s0*256 + j*4];
      float ss0 = ssrc[(size_t)s0*4+jh];
      float sc0 = ea0*wA;
      sc0 += __shfl_xor(sc0,1); sc0 += __shfl_xor(sc0,2);
      sc0 += __shfl_xor(sc0,4); sc0 += __shfl_xor(sc0,8);
      float v0 = sEa[t0*4+jh] + ss0 + sdn + sc0;
      v0 = v0>0.f ? v0 : 0.2f*v0;  v0 = fminf(v0,60.f);  float p0 = __expf(v0);
      float q0x=__shfl(p0,0), q0y=__shfl(p0,16), q0z=__shfl(p0,32), q0w=__shfl(p0,48);
      float4 eA = sEt4[t0*64+j];
      ds0 += q0x; ds1 += q0y; ds2 += q0z; ds3 += q0w;
      pa0 += q0x*(__uint_as_float(hA.x<<16)        +eA.x);
      pa1 += q0y*(__uint_as_float(hA.x&0xffff0000u)+eA.y);
      pa2 += q0z*(__uint_as_float(hA.y<<16)        +eA.z);
      pa3 += q0w*(__uint_as_float(hA.y&0xffff0000u)+eA.w);
      gacc += p0*ea0;
    }
    float r0=1.f/(ds0+1e-16f), r1=1.f/(ds1+1e-16f), r2=1.f/(ds2+1e-16f), r3=1.f/(ds3+1e-16f);
    float acc = pa0*r0 + pa1*r1 + pa2*r2 + pa3*r3;
    float rj = (jh==0?r0:jh==1?r1:jh==2?r2:r3);
    zfin[(size_t)n*64+j] += 0.25f*acc;   // plain RMW: single owner
    gsum[(size_t)n*64+j] = gacc*rj;
  }
}

// ---------------- layer2 finish + z output (FUSED k_fin + k_zout) ----------------
__global__ __launch_bounds__(256) void k_finz(
    const float* __restrict__ gsum, const void* __restrict__ We2,
    const int* __restrict__ flags, float* __restrict__ zfin, void* __restrict__ out){
  __shared__ float sW[16*256];    // 16KB: We2[k][c]
  __shared__ float sG[4][64];     // per-wave slabs
  int m15=flags[15], mo=flags[0];
  for (int i=threadIdx.x;i<16*256;i+=256) sW[i]=ldf(We2,i,m15);
  __syncthreads();
  int slot=threadIdx.x>>6, j=threadIdx.x&63;
  for (int nb=blockIdx.x; nb<NN/4; nb+=gridDim.x){
    int n = nb*4 + slot;
    sG[slot][j] = gsum[(size_t)n*64 + j];   // within-wave produce/consume
    float acc = 0.f;
    #pragma unroll
    for (int h=0;h<4;h++){
      float s=0.f;
      #pragma unroll
      for (int k=0;k<16;k++) s += sG[slot][h*16+k]*sW[k*256 + h*64 + j];
      acc += s;
    }
    float zf = zfin[(size_t)n*64+j] + 0.25f*acc;
    zfin[(size_t)n*64+j] = zf;                       // for k_dec
    stf(out, (size_t)NEL + (size_t)n*64 + j, mo, zf);
  }
}

// ---------------- edge decoder: MFMA ----------------
__global__ __launch_bounds__(256) void k_dec(
    const int* __restrict__ eli, const float* __restrict__ zfin,
    const void* __restrict__ W1, const u16* __restrict__ b1,
    const void* __restrict__ W2, const u16* __restrict__ b2,
    const int* __restrict__ flags,
    void* __restrict__ out){
  __shared__ v8s sB[4][4][64];   // [kb][ct][lane] = 8 bf16 of W1: col=ct*16+(l&15), k=kb*32+(l>>4)*8+i
  __shared__ float sB1[64], sW2[64];
  int m21=flags[21], m23=flags[23], mo=flags[0];
  for (int idx=threadIdx.x; idx<1024; idx+=256){
    int kb=idx>>8, ct=(idx>>6)&3, l=idx&63;
    int col = ct*16 + (l&15);
    int kbase = kb*32 + ((l>>4)<<3);
    short v[8];
    #pragma unroll
    for (int i=0;i<8;i++) v[i] = (short)f2b(ldf(W1,(size_t)(kbase+i)*64+col,m21));
    sB[kb][ct][l] = *(v8s*)v;
  }
  if (threadIdx.x<64){ sB1[threadIdx.x]=b2f(b1[threadIdx.x]); sW2[threadIdx.x]=ldf(W2,threadIdx.x,m23); }
  __syncthreads();
  float b2v = b2f(b2[0]);    // b1/b2 are zeros: u16 read valid under both dtypes
  int w = threadIdx.x>>6, lane = threadIdx.x&63;
  int l15 = lane&15, lk = lane>>4;
  int ngrp = NEL/64;   // 3125 (exact)
  for (int g = blockIdx.x; g < ngrp; g += gridDim.x){
    int e0 = g*64 + w*16;
    int eA = e0 + l15;
    int rn = eli[eA], cn = eli[NEL+eA];
    // A-frags: row=edge l15, k = kb*32 + lk*8 + i (8 consecutive; kb<2 -> row node, kb>=2 -> col node)
    v8s a[4];
    #pragma unroll
    for (int kb=0;kb<4;kb++){
      int k = kb*32 + lk*8;
      const float* src = (k<64) ? (zfin + (size_t)rn*64 + k) : (zfin + (size_t)cn*64 + (k-64));
      float4 f0 = *(const float4*)(src);
      float4 f1 = *(const float4*)(src+4);
      short v[8] = {(short)f2b(f0.x),(short)f2b(f0.y),(short)f2b(f0.z),(short)f2b(f0.w),
                    (short)f2b(f1.x),(short)f2b(f1.y),(short)f2b(f1.z),(short)f2b(f1.w)};
      a[kb] = *(v8s*)v;
    }
    // C: row(edge)=lk*4+r, col=ct*16+l15   [round-3-verified layout]
    float part[4] = {0,0,0,0};
    #pragma unroll
    for (int ct=0; ct<4; ct++){
      v4f c = {0.f,0.f,0.f,0.f};
      #pragma unroll
      for (int kb=0;kb<4;kb++)
        c = __builtin_amdgcn_mfma_f32_16x16x32_bf16(a[kb], sB[kb][ct][lane], c, 0,0,0);
      int col = ct*16 + l15;
      float w2c = sW2[col], b1c = sB1[col];
      #pragma unroll
      for (int r=0;r<4;r++) part[r] += fmaxf(c[r]+b1c, 0.f) * w2c;
    }
    // reduce over cols: sum across the 16 l15 lanes (same lk group)
    #pragma unroll
    for (int r=0;r<4;r++){
      float v = part[r];
      #pragma unroll
      for (int off=1; off<16; off<<=1) v += __shfl_xor(v, off);
      if (l15==0) stf(out, e0 + lk*4 + r, mo, v + b2v);
    }
  }
}

extern "C" void kernel_launch(void* const* d_in, const int* in_sizes, int n_in,
                              void* d_out, int out_size, void* d_ws, size_t ws_size,
                              hipStream_t stream){
  (void)in_sizes; (void)n_in;
  const void* x    =d_in[0];
  const int* ei    =(const int*)d_in[1];
  const int* ntype =(const int*)d_in[2];
  const void* eattr=d_in[3];
  const int* etype =(const int*)d_in[4];
  const int* eli   =(const int*)d_in[5];
  const void* Wx1=d_in[6];  const void* We1=d_in[7];  const void* nt1=d_in[8];
  const void* et1=d_in[9];  const void* as1=d_in[10]; const void* ad1=d_in[11];
  const void* ae1=d_in[12]; const void* res1=d_in[13];
  const void* Wx2=d_in[14]; const void* We2=d_in[15]; const void* nt2=d_in[16];
  const void* et2=d_in[17]; const void* as2=d_in[18]; const void* ad2=d_in[19];
  const void* ae2=d_in[20];
  const void* W1=d_in[21];  const u16* b1=(const u16*)d_in[22];
  const void* W2=d_in[23];  const u16* b2=(const u16*)d_in[24];

  const size_t NEED_BYTES = 30809572ULL * 4ULL;   // ~123.2 MB (layout kept; psort/rank slots now unused)
  if (ws_size < NEED_BYTES){
    k_stub<<<(out_size+255)/256,256,0,stream>>>((u16*)d_out, out_size);
    return;
  }
  float* ws=(float*)d_ws;
  size_t o=0;
  int*   flags=(int*)(ws+o); o+=32;
  float* We1a =ws+o; o+=64;
  float* et1a =ws+o; o+=96;
  float* We2a =ws+o; o+=64;
  float* et2a =ws+o; o+=96;                     // o = 352
  int*   cnt    =(int*)(ws+o); o+=NN;           // 100000
  int*   row_ptr=(int*)(ws+o); o+=NN+4;         // 100004 (padded)
  int*   perm   =(int*)(ws+o); o+=NE;
  int*   bsum   =(int*)(ws+o); o+=512;
  int*   boff   =(int*)(ws+o); o+=512;
  int*   rank   =(int*)(ws+o); o+=NE;           // unused (layout stability)
  int*   se     =(int*)(ws+o); o+=NE;
  u32*   Wxp    =(u32*)(ws+o); o+=8192;         // prepacked Wx2 bf16 pairs
  float* ssrc =ws+o; o+=(size_t)NN*4;
  float* sdst =ws+o; o+=(size_t)NN*4;
  float* psort=ws+o; o+=(size_t)NE*4;           // unused (layout stability)
  float* slotA=ws+o; o+=(size_t)NN*64;   // h1 (layer1) -> zfin (layer2)
  float* out1 =ws+o; o+=(size_t)NN*64;   // out1 (layer1) -> gsum (layer2)
  u16*   h2   =(u16*)(ws+o); o+=(size_t)NN*128;   // NN*256 bf16
  (void)rank; (void)psort;
  float* h1   = slotA;
  float* zfin = slotA;
  float* gsum = out1;                    // free after k5_node2 consumed out1

  const int NBLK = (NN+255)/256;   // 391

  k_detect<<<19,64,0,stream>>>(x,eattr,Wx1,We1,nt1,et1,as1,ad1,ae1,res1,
                               Wx2,We2,nt2,et2,as2,ad2,ae2,W1,W2,flags);
  k_fold<<<1,320,0,stream>>>(We1,ae1,et1,We2,ae2,et2,flags,We1a,et1a,We2a,et2a);
  k_pack<<<32,256,0,stream>>>(Wx2,flags,Wxp);
  // ---- CSR build (dst-sorted edge permutation + sorted payloads) ----
  k_zero<<<(NN+255)/256,256,0,stream>>>((float*)cnt, NN);
  k_hist<<<(NE+255)/256,256,0,stream>>>(ei, cnt);
  k_scan1<<<NBLK,256,0,stream>>>(cnt, row_ptr, bsum);
  k_scan2<<<1,512,0,stream>>>(bsum, boff);
  k_scan3<<<NBLK,256,0,stream>>>(row_ptr, boff);
  k_zero<<<(NN+255)/256,256,0,stream>>>((float*)cnt, NN);   // reset cursors
  k_scatter<<<(NE+255)/256,256,0,stream>>>(ei, etype, row_ptr, cnt, perm, se);
  // ---- layer 1 ----
  k1_node<<<(NN+255)/256,256,0,stream>>>(x,ntype,Wx1,nt1,res1,as1,ad1,flags,h1,out1,ssrc,sdst);
  k_msg1<<<NN/32,256,0,stream>>>(eattr,et1,We1,We1a,et1a,ssrc,sdst,h1,row_ptr,perm,se,flags,out1);
  k5_node2<<<NN/32,256,0,stream>>>(ntype,Wxp,nt2,as2,ad2,flags,out1,zfin,h2,ssrc,sdst);
  // ---- layer 2 ----
  k_msg2<<<NN/32,256,0,stream>>>(eattr,et2,We2a,et2a,ssrc,sdst,h2,row_ptr,perm,se,flags,zfin,gsum);
  k_finz<<<2048,256,0,stream>>>(gsum,We2,flags,zfin,d_out);
  k_dec<<<1024,256,0,stream>>>(eli,zfin,W1,b1,W2,b2,flags,d_out);
}